// Round 4
// baseline (383.038 us; speedup 1.0000x reference)
//
#include <hip/hip_runtime.h>
#include <hip/hip_bf16.h>

// Problem constants (from reference setup_inputs)
constexpr int BB = 2;
constexpr int L  = 24;
constexpr int C  = 32;
constexpr int H  = 128;
constexpr int W  = 256;
constexpr int HW = H * W;          // 32768
constexpr int R  = 32;
constexpr int LSTRIDE = C * HW;    // element stride between consecutive l-planes (4 MB!)

// Native 4-wide float vector (NOT HIP_vector_type — __builtin_nontemporal_store
// requires scalar/pointer/ext_vector types; R6 compile fix).
typedef float f32x4 __attribute__((ext_vector_type(4)));

// y[b,l,c,h,w] = sum_{t=0..l} k[c,t] * x[b,l-t,c,h,w]   (Lf=48 >= 2L-1: FFT == linear causal conv)
// k[c,t] = sum_r gamma[c,r] * exp(-t*nu[c,r]) * cos(t*theta[c,r])
//
// Evidence trail:
//  R1-R3 (prev session): inputs proven fp32; output fp32. absmax 0.25, passed.
//  R4: VGPR 56 -> 96 (loads genuinely hoisted, float4), VALUBusy 22->6%, dur UNCHANGED
//      (142 us, 2.1 TB/s). Two opposite loop structures hit the same wall => not an
//      issue-side MLP problem; memory-system cap for this pattern.
//  R5: FETCH == exactly half of x => y's 201 MB write stream evicts x from L3 between
//      bench iterations. y is write-once: store non-temporally.
//  R6: R5 failed to COMPILE (nontemporal builtin rejects HIP_vector_type); fixed with
//      ext_vector_type(4). R6 bench run died on container infra — resubmitting as R7.

// ---------------------------------------------------------------------------
// Kernel 1: k[c,t] precompute (768 values, 3 blocks — runs in a few µs)
// ---------------------------------------------------------------------------
__global__ __launch_bounds__(256) void k_precompute(const void* __restrict__ praw,
                                                    float* __restrict__ kk_out)
{
    // params dtype detection (wave-uniform, done by all lanes before any return)
    const int lane = threadIdx.x & 63;
    const unsigned int wp  = ((const unsigned int*)praw)[lane];
    const unsigned int hbp = (wp >> 8) & 0xFFu;
    const bool hitp = (hbp == 0xBFu) || (hbp == 0xC0u);   // nu_log in (-4.61,-1.5)
    const bool p_is_bf16 = __popcll(__ballot(hitp)) >= 32;

    const int id = blockIdx.x * 256 + threadIdx.x;        // 0 .. 767 (== C*L exactly)
    if (id >= C * L) return;
    const int c  = id / L;
    const int ti = id - c * L;
    const float t = (float)ti;

    float acc = 0.f;
    #pragma unroll 8
    for (int r = 0; r < R; ++r) {
        float p0, p1;
        if (p_is_bf16) {
            const __hip_bfloat16* pb = (const __hip_bfloat16*)praw;
            p0 = __bfloat162float(pb[c * R + r]);
            p1 = __bfloat162float(pb[C * R + c * R + r]);
        } else {
            const float* pf = (const float*)praw;
            p0 = pf[c * R + r];
            p1 = pf[C * R + c * R + r];
        }
        // identical expression order to the passing R3 kernel
        float nu    = expf(p0);
        float theta = expf(p1);
        float lam   = expf(-nu);
        float gamma = sqrtf(fmaxf(1.0f - lam * lam, 1e-12f));
        acc = fmaf(gamma * expf(-t * nu), cosf(t * theta), acc);
    }
    kk_out[id] = acc;   // layout (C, L)
}

// ---------------------------------------------------------------------------
// Kernel 2: streaming causal conv. One block = one (b,c) plane chunk of
// 1024 contiguous hw elements (256 threads x f32x4). All 24 l-plane loads
// issued up front; kk in SGPRs; y stored NON-TEMPORALLY (write-once data
// must not evict x from L2/L3).
// ---------------------------------------------------------------------------
__global__ __launch_bounds__(256) void convlru_main(
    const float* __restrict__ x,
    const float* __restrict__ kk_g,
    float* __restrict__ y)
{
    const int plane = blockIdx.y;          // b*C + c
    const int c = plane & (C - 1);
    const int b = plane >> 5;              // C == 32

    // ---- kernel row -> SGPRs (block-uniform loads; tiny, L2-resident) ----
    float kk[L];
    {
        const float* kc = kk_g + c * L;
        #pragma unroll
        for (int t = 0; t < L; ++t)
            kk[t] = __uint_as_float(
                __builtin_amdgcn_readfirstlane(__float_as_uint(kc[t])));
    }

    // Flat ELEMENT index of (b, l=0, c, hw). Fits in 32 bits (max ~50.3M).
    const unsigned int ebase = (unsigned int)(b * L * C + c) * (unsigned int)HW
                             + blockIdx.x * 1024u + threadIdx.x * 4u;
    const float* xb = x + ebase;
    float*       yb = y + ebase;

    // ---- issue ALL 24 l-plane loads up front: 24 x 16B/lane in flight ----
    f32x4 xv[L];
    #pragma unroll
    for (int l = 0; l < L; ++l)
        xv[l] = *(const f32x4*)(xb + (unsigned int)l * (unsigned int)LSTRIDE);

    // Keep the load cluster ahead of the conv (R4 structure, kept for stability).
    __builtin_amdgcn_sched_barrier(0);

    // ---- causal conv, fully unrolled; same t-ascending fmaf order as R3 ----
    #pragma unroll
    for (int l = 0; l < L; ++l) {
        f32x4 a = (f32x4)(0.f);
        #pragma unroll
        for (int t = 0; t <= l; ++t) {
            const f32x4 xt = xv[l - t];
            a.x = fmaf(kk[t], xt.x, a.x);
            a.y = fmaf(kk[t], xt.y, a.y);
            a.z = fmaf(kk[t], xt.z, a.z);
            a.w = fmaf(kk[t], xt.w, a.w);
        }
        // Non-temporal: y is write-once/never-read; do not allocate in L2/L3.
        __builtin_nontemporal_store(a,
            (f32x4*)(yb + (unsigned int)l * (unsigned int)LSTRIDE));
    }
}

extern "C" void kernel_launch(void* const* d_in, const int* in_sizes, int n_in,
                              void* d_out, int out_size, void* d_ws, size_t ws_size,
                              hipStream_t stream)
{
    // Robust input binding (unchanged from the passing kernel):
    // x has B*L*C*H*W = 50,331,648 elems; params has 2048.
    const void* x;
    const void* params;
    if (n_in >= 2 && in_sizes[0] == 2 * C * R) { params = d_in[0]; x = d_in[1]; }
    else                                        { x = d_in[0]; params = d_in[1]; }

    float* kk = (float*)d_ws;   // 768 floats = 3 KB of workspace

    k_precompute<<<dim3((C * L + 255) / 256), dim3(256), 0, stream>>>(params, kk);

    dim3 grid(HW / 1024, BB * C);   // (32, 64) = 2048 blocks
    convlru_main<<<grid, dim3(256), 0, stream>>>((const float*)x, kk, (float*)d_out);
}

// Round 5
// 349.518 us; speedup vs baseline: 1.0959x; 1.0959x over previous
//
#include <hip/hip_runtime.h>
#include <hip/hip_bf16.h>

// Problem constants (from reference setup_inputs)
constexpr int BB = 2;
constexpr int L  = 24;
constexpr int C  = 32;
constexpr int H  = 128;
constexpr int W  = 256;
constexpr int HW = H * W;          // 32768 elements per (b,l,c) plane slice (128 KB)
constexpr int R  = 32;
constexpr int LSTRIDE = C * HW;    // element stride between consecutive l-planes (4 MB!)

constexpr int CHUNK = 1024;        // floats per sub-chunk = 256 threads x f32x4
constexpr int WALK  = 4;           // sub-chunks walked sequentially by one block

typedef float f32x4 __attribute__((ext_vector_type(4)));

// y[b,l,c,h,w] = sum_{t=0..l} k[c,t] * x[b,l-t,c,h,w]   (Lf=48 >= 2L-1: FFT == linear causal conv)
// k[c,t] = sum_r gamma[c,r] * exp(-t*nu[c,r]) * cos(t*theta[c,r])
//
// Evidence trail:
//  R1-R3 (prev session): inputs proven fp32; output fp32. absmax 0.25, passed.
//  R4: loads hoisted (VGPR 96), VALUBusy 22->6%, dur UNCHANGED 142us => not issue-side MLP.
//  R7: NT stores: FETCH/WRITE/dur all unchanged (147us) => cache-policy theory dead.
//      Three structures all pin at 2.05-2.15 TB/s.
//  R8 (this round): last untested theory = instantaneous scatter. 2048+ concurrent blocks
//      each gathering 4KB at 4MB stride = ~100k active regions spanning 402MB -> DRAM
//      row/queue thrash. Fix: 512 blocks, each walks 4 consecutive 4KB sub-chunks per
//      plane (4x fewer active streams, 4-deep sequential locality per stream).

// ---------------------------------------------------------------------------
// Kernel 1: k[c,t] precompute (768 values — runs in a few µs)
// ---------------------------------------------------------------------------
__global__ __launch_bounds__(256) void k_precompute(const void* __restrict__ praw,
                                                    float* __restrict__ kk_out)
{
    // params dtype detection (wave-uniform, done by all lanes before any return)
    const int lane = threadIdx.x & 63;
    const unsigned int wp  = ((const unsigned int*)praw)[lane];
    const unsigned int hbp = (wp >> 8) & 0xFFu;
    const bool hitp = (hbp == 0xBFu) || (hbp == 0xC0u);   // nu_log in (-4.61,-1.5)
    const bool p_is_bf16 = __popcll(__ballot(hitp)) >= 32;

    const int id = blockIdx.x * 256 + threadIdx.x;        // 0 .. 767 (== C*L exactly)
    if (id >= C * L) return;
    const int c  = id / L;
    const int ti = id - c * L;
    const float t = (float)ti;

    float acc = 0.f;
    #pragma unroll 8
    for (int r = 0; r < R; ++r) {
        float p0, p1;
        if (p_is_bf16) {
            const __hip_bfloat16* pb = (const __hip_bfloat16*)praw;
            p0 = __bfloat162float(pb[c * R + r]);
            p1 = __bfloat162float(pb[C * R + c * R + r]);
        } else {
            const float* pf = (const float*)praw;
            p0 = pf[c * R + r];
            p1 = pf[C * R + c * R + r];
        }
        // identical expression order to the passing R3 kernel
        float nu    = expf(p0);
        float theta = expf(p1);
        float lam   = expf(-nu);
        float gamma = sqrtf(fmaxf(1.0f - lam * lam, 1e-12f));
        acc = fmaf(gamma * expf(-t * nu), cosf(t * theta), acc);
    }
    kk_out[id] = acc;   // layout (C, L)
}

// ---------------------------------------------------------------------------
// Kernel 2: streaming causal conv with sequential sub-chunk walking.
// One block = one (b,c) plane pair, walking WALK consecutive 4KB sub-chunks.
// Per sub-chunk: all 24 l-plane loads hoisted (24KB/wave in flight), then
// fully-unrolled causal conv, then 24 plane stores. kk lives in SGPRs.
// ---------------------------------------------------------------------------
__global__ __launch_bounds__(256) void convlru_main(
    const float* __restrict__ x,
    const float* __restrict__ kk_g,
    float* __restrict__ y)
{
    const int plane = blockIdx.y;          // b*C + c
    const int c = plane & (C - 1);
    const int b = plane >> 5;              // C == 32

    // ---- kernel row -> SGPRs (block-uniform loads; tiny, L2-resident) ----
    float kk[L];
    {
        const float* kc = kk_g + c * L;
        #pragma unroll
        for (int t = 0; t < L; ++t)
            kk[t] = __uint_as_float(
                __builtin_amdgcn_readfirstlane(__float_as_uint(kc[t])));
    }

    // Flat ELEMENT index of (b, l=0, c, hw-start). Fits in 32 bits (max ~50.3M).
    unsigned int ebase = (unsigned int)(b * L * C + c) * (unsigned int)HW
                       + blockIdx.x * (unsigned int)(CHUNK * WALK)
                       + threadIdx.x * 4u;

    #pragma unroll 1   // sequential walk — do NOT unroll (that would re-scatter)
    for (int s = 0; s < WALK; ++s, ebase += (unsigned int)CHUNK) {
        const float* xb = x + ebase;
        float*       yb = y + ebase;

        // ---- issue ALL 24 l-plane loads up front: 24 x 16B/lane in flight ----
        f32x4 xv[L];
        #pragma unroll
        for (int l = 0; l < L; ++l)
            xv[l] = *(const f32x4*)(xb + (unsigned int)l * (unsigned int)LSTRIDE);

        // Keep the load cluster ahead of the conv.
        __builtin_amdgcn_sched_barrier(0);

        // ---- causal conv, fully unrolled; same t-ascending fmaf order as R3 ----
        #pragma unroll
        for (int l = 0; l < L; ++l) {
            f32x4 a = (f32x4)(0.f);
            #pragma unroll
            for (int t = 0; t <= l; ++t) {
                const f32x4 xt = xv[l - t];
                a.x = fmaf(kk[t], xt.x, a.x);
                a.y = fmaf(kk[t], xt.y, a.y);
                a.z = fmaf(kk[t], xt.z, a.z);
                a.w = fmaf(kk[t], xt.w, a.w);
            }
            *(f32x4*)(yb + (unsigned int)l * (unsigned int)LSTRIDE) = a;
        }
    }
}

extern "C" void kernel_launch(void* const* d_in, const int* in_sizes, int n_in,
                              void* d_out, int out_size, void* d_ws, size_t ws_size,
                              hipStream_t stream)
{
    // Robust input binding (unchanged from the passing kernel):
    // x has B*L*C*H*W = 50,331,648 elems; params has 2048.
    const void* x;
    const void* params;
    if (n_in >= 2 && in_sizes[0] == 2 * C * R) { params = d_in[0]; x = d_in[1]; }
    else                                        { x = d_in[0]; params = d_in[1]; }

    float* kk = (float*)d_ws;   // 768 floats = 3 KB of workspace

    k_precompute<<<dim3((C * L + 255) / 256), dim3(256), 0, stream>>>(params, kk);

    // Grid: 8 walk-groups per plane x 64 planes = 512 blocks (2 per CU).
    dim3 grid(HW / (CHUNK * WALK), BB * C);
    convlru_main<<<grid, dim3(256), 0, stream>>>((const float*)x, kk, (float*)d_out);
}